// Round 15
// baseline (70.032 us; speedup 1.0000x reference)
//
#include <hip/hip_runtime.h>
#include <hip/hip_bf16.h>
#include <math.h>

#define B_ 4
#define T_ 2048
#define C_ 1024
#define H_ 128
#define SCALE 0.088388347648318447f   // 1/sqrt(128)

typedef unsigned short u16;
typedef __bf16 bf16x8 __attribute__((ext_vector_type(8)));
typedef float  f32x4  __attribute__((ext_vector_type(4)));
typedef u16    u16x8  __attribute__((ext_vector_type(8)));
typedef u16    u16x4  __attribute__((ext_vector_type(4)));

// ws byte offsets (ws ~256MB; all regions disjoint)
#define PO_OFF  0u            // bf16 [4][144][64][128] =  9,437,184 B
#define ML_OFF  18874368u     // f32 [4][144][2][64]    =    294,912 B
#define WF_OFF  19169280u     // bf16 W fragment-order  =    786,432 B
#define QB_OFF  19955712u     // bf16 [4][2048][128]    =  2,097,152 B
#define KF_OFF  22052864u     // bf16 K fragment-order  =  2,097,152 B
#define VF_OFF  24150016u     // bf16 V fragment-order  =  2,097,152 B

__device__ __forceinline__ u16 f2bf(float f) {
    __hip_bfloat16 h = __float2bfloat16(f);
    return __builtin_bit_cast(u16, h);
}
__device__ __forceinline__ float bf2f(u16 u) {
    unsigned v = (unsigned)u << 16;
    return __builtin_bit_cast(float, v);
}

// ---------------------------------------------------------------------------
// convert + permute W into B-fragment order:
// record (s, ntile=n>>4, kstep=k>>6, kc=(k>>5)&1): 64 lanes x 8 elems.
// lane = ((k>>3)&3)*16 + (n&15), elem j = k&7. SCALE folded into Wq (s=0).
// ---------------------------------------------------------------------------
__global__ __launch_bounds__(256) void convert_w(const float* __restrict__ Wq,
                                                 const float* __restrict__ Wk,
                                                 const float* __restrict__ Wv,
                                                 u16* __restrict__ wf) {
    const int id = blockIdx.x * 256 + threadIdx.x;      // < 3*131072
    const int s = id >> 17;
    const int r = id & 131071;
    const int k = r >> 7, n = r & 127;
    const float* W = (s == 0) ? Wq : (s == 1) ? Wk : Wv;
    float v = W[k * 128 + n];
    if (s == 0) v *= SCALE;
    const int ntile = n >> 4, kstep = k >> 6, kc = (k >> 5) & 1;
    const int lane = ((k >> 3) & 3) * 16 + (n & 15);
    const int j = k & 7;
    wf[((((size_t)(s * 8 + ntile) * 16 + kstep) * 2 + kc) * 64 + lane) * 8 + j] = f2bf(v);
}

// ---------------------------------------------------------------------------
// QKV GEMM, barrier-free main loop. grid (256, 3), block 256 (4 waves).
// x-tile [32][1024] staged to LDS ONCE (single barrier), W fragments loaded
// global->register (coalesced 1KB per wave-load, L2-resident).
// Wave w owns cols w*32..w*32+31 (2 N-tiles), rows 0..31 (2 M-tiles).
// Outputs: q row-major; K,V in attention-fragment order.
// ---------------------------------------------------------------------------
__global__ __launch_bounds__(256) void gemm_qkv(
    const float* __restrict__ x, const u16* __restrict__ wf,
    u16* __restrict__ qb, u16* __restrict__ kfr, u16* __restrict__ vfr)
{
    __shared__ u16 xs[32 * 1024];   // [32][1024] bf16, 2KB rows, byte ^((row&7)<<4)

    const int tid = threadIdx.x;
    const int w = tid >> 6, lane = tid & 63, lg = lane >> 4, lr = lane & 15;
    const int s = blockIdx.y;
    const int m0 = blockIdx.x * 32;

    // ---- stage x tile (contiguous 128KB fp32) once, bf16-converted, swizzled
    {
        const float* xt = x + (size_t)m0 * C_;
#pragma unroll
        for (int i = 0; i < 32; ++i) {               // 32*256*4 = 32768 floats
            const int fi = (i * 256 + tid) * 4;      // float index in tile
            const float4 f = *(const float4*)&xt[fi];
            const int row = fi >> 10, col = fi & 1023;
            u16x4 pk;
            pk[0] = f2bf(f.x); pk[1] = f2bf(f.y); pk[2] = f2bf(f.z); pk[3] = f2bf(f.w);
            *(u16x4*)((char*)xs + row * 2048 +
                      (((unsigned)col * 2) ^ (((unsigned)row & 7u) << 4))) = pk;
        }
    }
    __syncthreads();   // the ONLY barrier

    const u16* wbase = wf + (size_t)(s * 8) * 16 * 2 * 512 + (size_t)lane * 8;

    f32x4 acc[2][2] = {};
#pragma unroll 4
    for (int kstep = 0; kstep < 16; ++kstep) {
#pragma unroll
        for (int kc = 0; kc < 2; ++kc) {
            // kstep = 64 k = 128 B; kc = 32 k = 64 B; lg*8 k = 16 B
            const unsigned kbyte = (unsigned)(kstep * 128 + kc * 64 + lg * 16);
            bf16x8 af[2];
#pragma unroll
            for (int mi = 0; mi < 2; ++mi) {
                const int row = mi * 16 + lr;
                af[mi] = *(const bf16x8*)((const char*)xs + row * 2048 +
                                          (kbyte ^ (((unsigned)row & 7u) << 4)));
            }
#pragma unroll
            for (int ni = 0; ni < 2; ++ni) {
                const int ntile = w * 2 + ni;
                const bf16x8 bfr = *(const bf16x8*)(wbase +
                    (size_t)((ntile * 16 + kstep) * 2 + kc) * 512);
#pragma unroll
                for (int mi = 0; mi < 2; ++mi)
                    acc[mi][ni] = __builtin_amdgcn_mfma_f32_16x16x32_bf16(
                        af[mi], bfr, acc[mi][ni], 0, 0, 0);
            }
        }
    }

    // ---- epilogue
    if (s == 0) {
#pragma unroll
        for (int mi = 0; mi < 2; ++mi)
#pragma unroll
            for (int ni = 0; ni < 2; ++ni) {
                const int trow = m0 + mi * 16 + lg * 4;
                const int col = w * 32 + ni * 16 + lr;
#pragma unroll
                for (int r = 0; r < 4; ++r)
                    qb[(size_t)(trow + r) * H_ + col] = f2bf(acc[mi][ni][r]);
            }
    } else if (s == 1) {
        // K fragment order: rec (b, tloc, s2, kc), lane = (row&15)|(((d>>3)&3)<<4), j=d&7
#pragma unroll
        for (int mi = 0; mi < 2; ++mi)
#pragma unroll
            for (int ni = 0; ni < 2; ++ni) {
                const int d = w * 32 + ni * 16 + lr;
                const int kc = d >> 5, lsub = ((d >> 3) & 3) << 4, j = d & 7;
#pragma unroll
                for (int r = 0; r < 4; ++r) {
                    const int row = m0 + mi * 16 + lg * 4 + r;
                    const int bb = row >> 11, tloc = (row >> 5) & 63;
                    const int s2 = (row >> 4) & 1, rr = row & 15;
                    kfr[(((size_t)((bb * 64 + tloc) * 2 + s2) * 4 + kc) * 64 +
                         (rr | lsub)) * 8 + j] = f2bf(acc[mi][ni][r]);
                }
            }
    } else {
        // V fragment order: rec (b, tloc, nid=d>>4), lane = (d&15)|(g<<4),
        // g=(kv&15)>>2, j=(kv>>4)*4+(kv&3)
#pragma unroll
        for (int mi = 0; mi < 2; ++mi)
#pragma unroll
            for (int ni = 0; ni < 2; ++ni) {
                const int d = w * 32 + ni * 16 + lr;
                const int nid = d >> 4;
#pragma unroll
                for (int r = 0; r < 4; ++r) {
                    const int row = m0 + mi * 16 + lg * 4 + r;
                    const int bb = row >> 11, tloc = (row >> 5) & 63, kv = row & 31;
                    const int g = (kv & 15) >> 2, j = (kv >> 4) * 4 + (kv & 3);
                    vfr[(((size_t)(bb * 64 + tloc) * 8 + nid) * 64 +
                         ((g << 4) | (d & 15))) * 8 + j] = f2bf(acc[mi][ni][r]);
                }
            }
    }
}

// ---------------------------------------------------------------------------
// Flash attention, split-K, ZERO LDS / ZERO barriers: K and V fragments are
// loaded global->register (L2-resident, coalesced 1KB wave-loads).
// grid (32 jt, 8 split, 4 batch), block 256 (4 waves, 16 q-rows each).
// defer-max softmax; bf16 partials.
// ---------------------------------------------------------------------------
__global__ __launch_bounds__(256) void attn_split(
    const u16* __restrict__ qb, const u16* __restrict__ kfr,
    const u16* __restrict__ vfr, u16* __restrict__ po, float* __restrict__ ml)
{
    const int jt = blockIdx.x, sp = blockIdx.y, b = blockIdx.z;
    const int kt0 = sp * 8;
    const int ktend_all = 2 * jt + 2;
    if (kt0 >= ktend_all) return;
    const int kt_end = min(kt0 + 8, ktend_all);

    const int tid = threadIdx.x;
    const int w = tid >> 6, lane = tid & 63, lg = lane >> 4, lr = lane & 15;
    const int qrow_base = jt * 64 + w * 16;

    // Q fragments (row-major, d-slot map kc*32+lg*8+j matches K-frag map)
    const u16* qp = qb + ((size_t)(b << 11) + qrow_base + lr) * H_;
    bf16x8 qf[4];
#pragma unroll
    for (int kc = 0; kc < 4; ++kc)
        qf[kc] = *(const bf16x8*)&qp[kc * 32 + lg * 8];

    const u16* kfb = kfr + (size_t)(b * 64) * 4096 + (size_t)lane * 8;
    const u16* vfb = vfr + (size_t)(b * 64) * 4096 + (size_t)lane * 8;

    f32x4 o[8] = {};
    float m_run = -1e30f, l_run = 0.f;

#pragma unroll 2
    for (int kt = kt0; kt < kt_end; ++kt) {
        const u16* kft = kfb + (size_t)kt * 4096;
        const u16* vft = vfb + (size_t)kt * 4096;
        bf16x8 kf0[4], kf1[4], vf[8];
#pragma unroll
        for (int kc = 0; kc < 4; ++kc) {
            kf0[kc] = *(const bf16x8*)(kft + kc * 512);
            kf1[kc] = *(const bf16x8*)(kft + (4 + kc) * 512);
        }
#pragma unroll
        for (int ni = 0; ni < 8; ++ni)
            vf[ni] = *(const bf16x8*)(vft + ni * 512);

        // ---- S^T = K @ Q^T
        f32x4 s0 = {0.f, 0.f, 0.f, 0.f}, s1 = {0.f, 0.f, 0.f, 0.f};
#pragma unroll
        for (int kc = 0; kc < 4; ++kc) {
            s0 = __builtin_amdgcn_mfma_f32_16x16x32_bf16(kf0[kc], qf[kc], s0, 0, 0, 0);
            s1 = __builtin_amdgcn_mfma_f32_16x16x32_bf16(kf1[kc], qf[kc], s1, 0, 0, 0);
        }

        // causal mask (boundary tiles only), global indices
        if (kt * 32 + 31 > qrow_base) {
            const int qg = qrow_base + lr;
            const int kvb = kt * 32 + lg * 4;
#pragma unroll
            for (int r = 0; r < 4; ++r) {
                if (kvb + r > qg)      s0[r] = -INFINITY;
                if (kvb + 16 + r > qg) s1[r] = -INFINITY;
            }
        }

        // online softmax with defer-max (q-row = lr, replicated across lane-groups)
        float mt = fmaxf(fmaxf(fmaxf(s0[0], s0[1]), fmaxf(s0[2], s0[3])),
                         fmaxf(fmaxf(s1[0], s1[1]), fmaxf(s1[2], s1[3])));
        mt = fmaxf(mt, __shfl_xor(mt, 16));
        mt = fmaxf(mt, __shfl_xor(mt, 32));
        if (__any(mt > m_run + 8.f)) {
            const float mn = fmaxf(m_run, mt);
            const float f = __expf(m_run - mn);
            const float fb0 = __shfl(f, lg * 4 + 0);
            const float fb1 = __shfl(f, lg * 4 + 1);
            const float fb2 = __shfl(f, lg * 4 + 2);
            const float fb3 = __shfl(f, lg * 4 + 3);
#pragma unroll
            for (int ni = 0; ni < 8; ++ni) {
                o[ni][0] *= fb0; o[ni][1] *= fb1; o[ni][2] *= fb2; o[ni][3] *= fb3;
            }
            l_run *= f;
            m_run = mn;
        }
        const float p0 = __expf(s0[0] - m_run), p1 = __expf(s0[1] - m_run);
        const float p2 = __expf(s0[2] - m_run), p3 = __expf(s0[3] - m_run);
        const float p4 = __expf(s1[0] - m_run), p5 = __expf(s1[1] - m_run);
        const float p6 = __expf(s1[2] - m_run), p7 = __expf(s1[3] - m_run);
        float sum = ((p0 + p1) + (p2 + p3)) + ((p4 + p5) + (p6 + p7));
        sum += __shfl_xor(sum, 16);
        sum += __shfl_xor(sum, 32);
        l_run += sum;

        // P -> bf16 A-frag (slot (g,j) -> kv = 4g + (j&3) + 16*(j>>2))
        bf16x8 pa;
        pa[0] = (__bf16)p0; pa[1] = (__bf16)p1; pa[2] = (__bf16)p2; pa[3] = (__bf16)p3;
        pa[4] = (__bf16)p4; pa[5] = (__bf16)p5; pa[6] = (__bf16)p6; pa[7] = (__bf16)p7;

        // PV: O[16q x 128d] += P @ V (vf matches the same kv-slot map)
#pragma unroll
        for (int ni = 0; ni < 8; ++ni)
            o[ni] = __builtin_amdgcn_mfma_f32_16x16x32_bf16(pa, vf[ni], o[ni], 0, 0, 0);
    }

    // write partials (bf16)
    const int a = jt >> 2, b3 = jt & 3;
    const int slot = (a + 1) * (2 * a + b3) + sp;
    u16* pob = po + (size_t)(b * 144 + slot) * 64 * 128;
#pragma unroll
    for (int ni = 0; ni < 8; ++ni) {
        const int col = ni * 16 + lr;
#pragma unroll
        for (int rj = 0; rj < 4; ++rj)
            pob[(w * 16 + lg * 4 + rj) * 128 + col] = f2bf(o[ni][rj]);
    }
    if (lg == 0) {
        float* mlb = ml + (size_t)(b * 144 + slot) * 128;
        mlb[w * 16 + lr] = m_run;
        mlb[64 + w * 16 + lr] = l_run;
    }
}

// ---------------------------------------------------------------------------
// Combine split-K partials (up to 8, bf16 po). grid (256, 4), block 256.
// ---------------------------------------------------------------------------
__global__ __launch_bounds__(256) void attn_combine(
    const u16* __restrict__ po, const float* __restrict__ ml,
    float* __restrict__ out)
{
    const int rid = (blockIdx.x << 3) + (threadIdx.x >> 5);   // row in batch
    const int b = blockIdx.y;
    const int d4 = (threadIdx.x & 31) * 4;
    const int jt = rid >> 6, row = rid & 63;
    const int a = jt >> 2, b3 = jt & 3;
    const int slot0 = (a + 1) * (2 * a + b3);
    const int c = a + 1;                                       // active splits

    float M = -INFINITY;
#pragma unroll
    for (int si = 0; si < 8; ++si)
        if (si < c) M = fmaxf(M, ml[(size_t)(b * 144 + slot0 + si) * 128 + row]);

    float L = 0.f;
    float a0 = 0.f, a1 = 0.f, a2 = 0.f, a3 = 0.f;
#pragma unroll
    for (int si = 0; si < 8; ++si) {
        if (si < c) {
            const float* mlb = ml + (size_t)(b * 144 + slot0 + si) * 128;
            const float wgt = __expf(mlb[row] - M);
            L += wgt * mlb[64 + row];
            const u16x4 t = *(const u16x4*)&po[((size_t)(b * 144 + slot0 + si) * 64 + row) * 128 + d4];
            a0 = fmaf(wgt, bf2f(t[0]), a0); a1 = fmaf(wgt, bf2f(t[1]), a1);
            a2 = fmaf(wgt, bf2f(t[2]), a2); a3 = fmaf(wgt, bf2f(t[3]), a3);
        }
    }
    const float inv = 1.f / L;
    *(float4*)&out[((size_t)(b << 11) + rid) * H_ + d4] =
        make_float4(a0 * inv, a1 * inv, a2 * inv, a3 * inv);
}

extern "C" void kernel_launch(void* const* d_in, const int* in_sizes, int n_in,
                              void* d_out, int out_size, void* d_ws, size_t ws_size,
                              hipStream_t stream) {
    const float* x  = (const float*)d_in[0];
    const float* Wk = (const float*)d_in[1];
    const float* Wq = (const float*)d_in[2];
    const float* Wv = (const float*)d_in[3];
    float* out = (float*)d_out;

    u16* po   = (u16*)((char*)d_ws + PO_OFF);
    float* ml = (float*)((char*)d_ws + ML_OFF);
    u16* wf   = (u16*)((char*)d_ws + WF_OFF);
    u16* qb   = (u16*)((char*)d_ws + QB_OFF);
    u16* kfr  = (u16*)((char*)d_ws + KF_OFF);
    u16* vfr  = (u16*)((char*)d_ws + VF_OFF);

    convert_w<<<1536, 256, 0, stream>>>(Wq, Wk, Wv, wf);
    gemm_qkv<<<dim3(256, 3), 256, 0, stream>>>(x, wf, qb, kfr, vfr);
    attn_split<<<dim3(32, 8, 4), 256, 0, stream>>>(qb, kfr, vfr, po, ml);
    attn_combine<<<dim3(256, 4), 256, 0, stream>>>(po, ml, out);
}